// Round 2
// baseline (1646.028 us; speedup 1.0000x reference)
//
#include <hip/hip_runtime.h>
#include <hip/hip_bf16.h>

// Problem: 2-layer GCN, N=100000 nodes, E=1600000 edges, 64 -> 64 -> 1.
// Inputs (setup_inputs order):
//   0: x           [N,64]  f32
//   1: edge_index  [2,E]   delivered as int32 by harness (integer -> const int*)
//   2: edge_weight [E]     f32
//   3: W1          [64,64] f32
//   4: b1          [64]    f32
//   5: W2          [64,1]  f32
//   6: b2          [1]     f32
// Output: [N,1] f32
//
// Pipeline:
//   K1a: deg[i] = 1 (self-loop weight)
//   K1b: deg[col[e]] += w[e]            (scalar atomics)
//   K2 : h1 = x@W1 ; dinv = rsqrt(deg) ; out1 = h1/deg (self-loop init)
//   K3 : out1[c] += h1[r] * (dinv[r]*w*dinv[c])   (16 lanes/edge, float4, atomics)
//   K4 : h2[i] = sum_c relu(out1[i]+b1)*W2 ; out2[i] = b2 + h2[i]*dinv[i]^2
//   K5 : out2[c] += h2[r] * norm        (1 scalar atomic per edge)

#define N_NODES 100000
#define N_EDGES 1600000

__global__ void deg_init(float* __restrict__ deg, int n) {
    int i = blockIdx.x * blockDim.x + threadIdx.x;
    if (i < n) deg[i] = 1.0f;   // self-loop weight
}

__global__ void deg_acc(const int* __restrict__ idx,
                        const float* __restrict__ w,
                        float* __restrict__ deg, int E) {
    int e = blockIdx.x * blockDim.x + threadIdx.x;
    if (e < E) atomicAdd(&deg[idx[E + e]], w[e]);
}

// 16 rows per block; W1 (16KB) + 16 x-rows (4KB) staged in LDS.
__global__ void gemm1_selfinit(const float* __restrict__ x,
                               const float* __restrict__ W1,
                               const float* __restrict__ deg,
                               float* __restrict__ h1,
                               float* __restrict__ out1,
                               float* __restrict__ dinv) {
    __shared__ float w1s[64 * 64];
    __shared__ float xs[16 * 64];
    __shared__ float invd[16];
    int t = threadIdx.x;
    int row0 = blockIdx.x * 16;

    const float4* W4 = (const float4*)W1;
    float4* w1s4 = (float4*)w1s;
#pragma unroll
    for (int i = 0; i < 4; i++) w1s4[t + 256 * i] = W4[t + 256 * i];
    ((float4*)xs)[t] = ((const float4*)(x + (size_t)row0 * 64))[t];
    if (t < 16) {
        float d = deg[row0 + t];
        invd[t] = 1.0f / d;          // self-loop norm = dinv^2 = 1/deg
        dinv[row0 + t] = rsqrtf(d);
    }
    __syncthreads();

    int col = t & 63;
    int r0 = t >> 6;  // 0..3, constant within a wave
    float acc0 = 0.f, acc1 = 0.f, acc2 = 0.f, acc3 = 0.f;
#pragma unroll
    for (int k = 0; k < 64; k++) {
        float wv = w1s[k * 64 + col];
        acc0 += xs[(r0     ) * 64 + k] * wv;
        acc1 += xs[(r0 +  4) * 64 + k] * wv;
        acc2 += xs[(r0 +  8) * 64 + k] * wv;
        acc3 += xs[(r0 + 12) * 64 + k] * wv;
    }
    float accs[4] = {acc0, acc1, acc2, acc3};
#pragma unroll
    for (int j = 0; j < 4; j++) {
        int r = r0 + 4 * j;
        size_t g = (size_t)(row0 + r) * 64 + col;
        h1[g] = accs[j];
        out1[g] = accs[j] * invd[r];
    }
}

// Layer-1 edge aggregation: 16 lanes per edge, float4 per lane.
__global__ void edge_agg1(const int* __restrict__ idx,
                          const float* __restrict__ wgt,
                          const float* __restrict__ dinv,
                          const float* __restrict__ h1,
                          float* __restrict__ out1, int E) {
    int tid = blockIdx.x * blockDim.x + threadIdx.x;
    int e = tid >> 4;
    if (e >= E) return;
    int l = tid & 15;
    int r = idx[e];
    int c = idx[E + e];
    float norm = dinv[r] * wgt[e] * dinv[c];
    float4 v = ((const float4*)(h1 + (size_t)r * 64))[l];
    float* dst = out1 + (size_t)c * 64 + l * 4;
    atomicAdd(dst + 0, v.x * norm);
    atomicAdd(dst + 1, v.y * norm);
    atomicAdd(dst + 2, v.z * norm);
    atomicAdd(dst + 3, v.w * norm);
}

// One wave per row: relu(out1+b1) dot W2 -> h2; init out2 with bias + self-loop.
__global__ void layer2_proj(const float* __restrict__ out1,
                            const float* __restrict__ b1,
                            const float* __restrict__ W2,
                            const float* __restrict__ b2,
                            const float* __restrict__ dinv,
                            float* __restrict__ h2,
                            float* __restrict__ out2, int n) {
    int t = threadIdx.x;
    int lane = t & 63;
    int wv = t >> 6;
    int row = blockIdx.x * 4 + wv;
    if (row >= n) return;
    float v = out1[(size_t)row * 64 + lane] + b1[lane];
    v = fmaxf(v, 0.0f);
    float p = v * W2[lane];
#pragma unroll
    for (int off = 32; off > 0; off >>= 1) p += __shfl_xor(p, off, 64);
    if (lane == 0) {
        float di = dinv[row];
        h2[row] = p;
        out2[row] = b2[0] + p * di * di;
    }
}

// Layer-2 edge aggregation: one scalar atomic per edge.
__global__ void edge_agg2(const int* __restrict__ idx,
                          const float* __restrict__ wgt,
                          const float* __restrict__ dinv,
                          const float* __restrict__ h2,
                          float* __restrict__ out2, int E) {
    int e = blockIdx.x * blockDim.x + threadIdx.x;
    if (e >= E) return;
    int r = idx[e];
    int c = idx[E + e];
    float norm = dinv[r] * wgt[e] * dinv[c];
    atomicAdd(&out2[c], h2[r] * norm);
}

extern "C" void kernel_launch(void* const* d_in, const int* in_sizes, int n_in,
                              void* d_out, int out_size, void* d_ws, size_t ws_size,
                              hipStream_t stream) {
    const float* x   = (const float*)d_in[0];
    const int*   idx = (const int*)d_in[1];      // int32 per harness contract
    const float* ew  = (const float*)d_in[2];
    const float* W1  = (const float*)d_in[3];
    const float* b1  = (const float*)d_in[4];
    const float* W2  = (const float*)d_in[5];
    const float* b2  = (const float*)d_in[6];
    float* out = (float*)d_out;

    const int N = N_NODES;
    const int E = N_EDGES;

    // Workspace layout (floats): deg[N] | dinv[N] | h1[N*64] | out1[N*64] | h2[N]
    // Total = N*131*4 = 52.4 MB.
    float* ws   = (float*)d_ws;
    float* deg  = ws;
    float* dinv = ws + N;
    float* h1   = ws + 2 * (size_t)N;
    float* out1 = h1 + (size_t)N * 64;
    float* h2   = out1 + (size_t)N * 64;

    deg_init<<<(N + 255) / 256, 256, 0, stream>>>(deg, N);
    deg_acc<<<(E + 255) / 256, 256, 0, stream>>>(idx, ew, deg, E);
    gemm1_selfinit<<<N / 16, 256, 0, stream>>>(x, W1, deg, h1, out1, dinv);
    edge_agg1<<<(E * 16 + 255) / 256, 256, 0, stream>>>(idx, ew, dinv, h1, out1, E);
    layer2_proj<<<(N + 3) / 4, 256, 0, stream>>>(out1, b1, W2, b2, dinv, h2, out, N);
    edge_agg2<<<(E + 255) / 256, 256, 0, stream>>>(idx, ew, dinv, h2, out, E);
}

// Round 3
// 420.701 us; speedup vs baseline: 3.9126x; 3.9126x over previous
//
#include <hip/hip_runtime.h>
#include <hip/hip_bf16.h>

// 2-layer GCN, N=100000, E=1600000, 64 -> 64 -> 1, f32.
// Round-2 profile: edge_agg1 atomics = 1.6 GB WRITE_SIZE (16 B per f32 atomic,
// device-scope atomics bypass L2 write-absorption) -> 1357 us. Fix: on-device
// counting sort by destination (CSC), then atomic-free gather aggregation.
//
// Pipeline:
//   K0 init   : zero cnt/cursor/deg
//   K1 hist   : cnt[c]++ ; deg[c] += w          (atomics to 400KB tables)
//   K2 dinv   : dinv = rsqrt(1+deg)
//   K3-5 scan : off = exclusive_scan(cnt)        (3 tiny kernels)
//   K6 gemm1  : h1 = x @ W1                      (LDS-staged, writes h1 only)
//   K7 scatter: pairs[off[c]+cur[c]++] = (r, dinv[r]*w*dinv[c])
//   K8 gather1: per-dst wave: acc = dinv^2*h1[dst] + sum norm*h1[src]
//               fused: z = relu(acc+b1).W2 -> h2[dst]; out[dst]=b2+z*dinv^2
//   K9 gather2: per-dst thread: out[dst] += sum norm*h2[src]

#define N_NODES 100000
#define N_EDGES 1600000
#define SCAN_BLOCKS 391   // ceil(100000/256)

__global__ void init_zero(int* __restrict__ p, int n) {
    int i = blockIdx.x * blockDim.x + threadIdx.x;
    if (i < n) p[i] = 0;
}

__global__ void hist(const int* __restrict__ idx, const float* __restrict__ w,
                     int* __restrict__ cnt, float* __restrict__ deg, int E) {
    int e = blockIdx.x * blockDim.x + threadIdx.x;
    if (e >= E) return;
    int c = idx[E + e];
    atomicAdd(&cnt[c], 1);
    atomicAdd(&deg[c], w[e]);
}

__global__ void dinv_k(const float* __restrict__ deg, float* __restrict__ dinv, int n) {
    int i = blockIdx.x * blockDim.x + threadIdx.x;
    if (i < n) dinv[i] = rsqrtf(1.0f + deg[i]);   // +1 = self-loop weight
}

// Per-block inclusive scan -> exclusive offsets + block totals.
__global__ void scan1(const int* __restrict__ cnt, int* __restrict__ off,
                      int* __restrict__ bsum, int n) {
    __shared__ int s[256];
    int t = threadIdx.x;
    int i = blockIdx.x * 256 + t;
    int v = (i < n) ? cnt[i] : 0;
    s[t] = v;
    __syncthreads();
#pragma unroll
    for (int d = 1; d < 256; d <<= 1) {
        int u = (t >= d) ? s[t - d] : 0;
        __syncthreads();
        s[t] += u;
        __syncthreads();
    }
    if (i < n) off[i] = s[t] - v;
    if (t == 255) bsum[blockIdx.x] = s[255];
}

// Exclusive scan of block totals (single block, 512 threads >= SCAN_BLOCKS).
__global__ void scan2(int* __restrict__ bsum, int nb) {
    __shared__ int s[512];
    int t = threadIdx.x;
    int v = (t < nb) ? bsum[t] : 0;
    s[t] = v;
    __syncthreads();
#pragma unroll
    for (int d = 1; d < 512; d <<= 1) {
        int u = (t >= d) ? s[t - d] : 0;
        __syncthreads();
        s[t] += u;
        __syncthreads();
    }
    if (t < nb) bsum[t] = s[t] - v;
}

__global__ void scan3(int* __restrict__ off, const int* __restrict__ bsum, int n) {
    int i = blockIdx.x * 256 + threadIdx.x;
    if (i < n) off[i] += bsum[blockIdx.x];
}

// 16 rows/block; W1 (16KB) + 16 x-rows (4KB) in LDS. Writes h1 only.
__global__ void gemm1(const float* __restrict__ x, const float* __restrict__ W1,
                      float* __restrict__ h1) {
    __shared__ float w1s[64 * 64];
    __shared__ float xs[16 * 64];
    int t = threadIdx.x;
    int row0 = blockIdx.x * 16;

    const float4* W4 = (const float4*)W1;
    float4* w1s4 = (float4*)w1s;
#pragma unroll
    for (int i = 0; i < 4; i++) w1s4[t + 256 * i] = W4[t + 256 * i];
    ((float4*)xs)[t] = ((const float4*)(x + (size_t)row0 * 64))[t];
    __syncthreads();

    int col = t & 63;
    int r0 = t >> 6;
    float acc0 = 0.f, acc1 = 0.f, acc2 = 0.f, acc3 = 0.f;
#pragma unroll
    for (int k = 0; k < 64; k++) {
        float wv = w1s[k * 64 + col];
        acc0 += xs[(r0     ) * 64 + k] * wv;
        acc1 += xs[(r0 +  4) * 64 + k] * wv;
        acc2 += xs[(r0 +  8) * 64 + k] * wv;
        acc3 += xs[(r0 + 12) * 64 + k] * wv;
    }
    float accs[4] = {acc0, acc1, acc2, acc3};
#pragma unroll
    for (int j = 0; j < 4; j++)
        h1[(size_t)(row0 + r0 + 4 * j) * 64 + col] = accs[j];
}

// Sort edges by destination; store (src, norm) pairs per segment.
__global__ void scatter(const int* __restrict__ idx, const float* __restrict__ w,
                        const float* __restrict__ dinv, const int* __restrict__ off,
                        int* __restrict__ cursor, float2* __restrict__ pairs, int E) {
    int e = blockIdx.x * blockDim.x + threadIdx.x;
    if (e >= E) return;
    int r = idx[e];
    int c = idx[E + e];
    float norm = dinv[r] * w[e] * dinv[c];
    int pos = off[c] + atomicAdd(&cursor[c], 1);
    pairs[pos] = make_float2(__int_as_float(r), norm);
}

// One wave per dst: 64-channel gather-aggregate, fused relu+b1+W2 projection.
__global__ void gather1(const float* __restrict__ h1, const float2* __restrict__ pairs,
                        const int* __restrict__ off, const int* __restrict__ cnt,
                        const float* __restrict__ dinv, const float* __restrict__ b1,
                        const float* __restrict__ W2, const float* __restrict__ b2,
                        float* __restrict__ h2, float* __restrict__ out, int n) {
    int t = threadIdx.x;
    int lane = t & 63;
    int dst = blockIdx.x * 4 + (t >> 6);
    if (dst >= n) return;
    int beg = off[dst];
    int end = beg + cnt[dst];
    float di = dinv[dst];
    float acc = h1[(size_t)dst * 64 + lane] * di * di;   // self-loop term
    float a0 = 0.f, a1 = 0.f, a2 = 0.f, a3 = 0.f;
    int j = beg;
    for (; j + 4 <= end; j += 4) {
        float2 p0 = pairs[j], p1 = pairs[j + 1], p2 = pairs[j + 2], p3 = pairs[j + 3];
        float v0 = h1[(size_t)__float_as_int(p0.x) * 64 + lane];
        float v1 = h1[(size_t)__float_as_int(p1.x) * 64 + lane];
        float v2 = h1[(size_t)__float_as_int(p2.x) * 64 + lane];
        float v3 = h1[(size_t)__float_as_int(p3.x) * 64 + lane];
        a0 += p0.y * v0; a1 += p1.y * v1; a2 += p2.y * v2; a3 += p3.y * v3;
    }
    for (; j < end; j++) {
        float2 p = pairs[j];
        a0 += p.y * h1[(size_t)__float_as_int(p.x) * 64 + lane];
    }
    acc += (a0 + a1) + (a2 + a3);
    float v = fmaxf(acc + b1[lane], 0.0f);
    float p = v * W2[lane];
#pragma unroll
    for (int offl = 32; offl > 0; offl >>= 1) p += __shfl_xor(p, offl, 64);
    if (lane == 0) {
        h2[dst] = p;
        out[dst] = b2[0] + p * di * di;   // bias + layer-2 self-loop
    }
}

// One thread per dst: out[dst] += sum norm * h2[src].
__global__ void gather2(const float2* __restrict__ pairs, const int* __restrict__ off,
                        const int* __restrict__ cnt, const float* __restrict__ h2,
                        float* __restrict__ out, int n) {
    int i = blockIdx.x * blockDim.x + threadIdx.x;
    if (i >= n) return;
    int beg = off[i];
    int end = beg + cnt[i];
    float s = 0.f;
#pragma unroll 4
    for (int j = beg; j < end; j++) {
        float2 p = pairs[j];
        s += p.y * h2[__float_as_int(p.x)];
    }
    out[i] += s;
}

extern "C" void kernel_launch(void* const* d_in, const int* in_sizes, int n_in,
                              void* d_out, int out_size, void* d_ws, size_t ws_size,
                              hipStream_t stream) {
    const float* x   = (const float*)d_in[0];
    const int*   idx = (const int*)d_in[1];      // int32 per harness contract
    const float* ew  = (const float*)d_in[2];
    const float* W1  = (const float*)d_in[3];
    const float* b1  = (const float*)d_in[4];
    const float* W2  = (const float*)d_in[5];
    const float* b2  = (const float*)d_in[6];
    float* out = (float*)d_out;

    const int N = N_NODES;
    const int E = N_EDGES;

    // ws layout (float units):
    // cnt[N] | cursor[N] | deg[N] | dinv[N] | off[N] | bsum[512] | pairs[2E] | h1[N*64] | h2[N]
    float* ws    = (float*)d_ws;
    int*   cnt   = (int*)ws;
    int*   cur   = (int*)(ws + N);
    float* deg   = ws + 2 * (size_t)N;
    float* dinv  = ws + 3 * (size_t)N;
    int*   off   = (int*)(ws + 4 * (size_t)N);
    int*   bsum  = (int*)(ws + 5 * (size_t)N);            // 512 ints
    float2* pairs= (float2*)(ws + 5 * (size_t)N + 512);   // byte off 2002048, 8-aligned
    float* h1    = ws + 5 * (size_t)N + 512 + 2 * (size_t)E;  // 16-aligned
    float* h2    = h1 + (size_t)N * 64;
    // total = 10,200,512 floats = 40.8 MB

    init_zero<<<(3 * N + 255) / 256, 256, 0, stream>>>(cnt, 3 * N);  // cnt, cur, deg
    hist<<<(E + 255) / 256, 256, 0, stream>>>(idx, ew, cnt, deg, E);
    dinv_k<<<(N + 255) / 256, 256, 0, stream>>>(deg, dinv, N);
    scan1<<<SCAN_BLOCKS, 256, 0, stream>>>(cnt, off, bsum, N);
    scan2<<<1, 512, 0, stream>>>(bsum, SCAN_BLOCKS);
    scan3<<<SCAN_BLOCKS, 256, 0, stream>>>(off, bsum, N);
    gemm1<<<N / 16, 256, 0, stream>>>(x, W1, h1);
    scatter<<<(E + 255) / 256, 256, 0, stream>>>(idx, ew, dinv, off, cur, pairs, E);
    gather1<<<(N + 3) / 4, 256, 0, stream>>>(h1, pairs, off, cnt, dinv, b1, W2, b2, h2, out, N);
    gather2<<<(N + 255) / 256, 256, 0, stream>>>(pairs, off, cnt, h2, out, N);
}

// Round 5
// 304.192 us; speedup vs baseline: 5.4112x; 1.3830x over previous
//
#include <hip/hip_runtime.h>
#include <hip/hip_bf16.h>

// 2-layer GCN, N=100000, E=1600000, 64 -> 64 -> 1, f32.
// Round-3 profile: hist = 146us, 3.2M atomics to 100K addrs (16-way avg
// contention, 22 G atomics/s, VALUBusy 0.3%). Fix: single packed 64-bit
// atomic per edge (count in high 22 bits, fixed-point weight sum in low 42),
// whose RETURN VALUE is the counting-sort rank -> scatter becomes atomic-free.
// (Round 4 = resubmit: GPU broker timeout, kernel never ran.)
//
// Pipeline:
//   K0 init   : zero packed[N] (800KB)
//   K1 hist   : old = atomicAdd(packed[c], (1<<42)|fix32(w)); rank[e]=old>>42
//   K2 scan1  : unpack cnt, dinv=rsqrt(1+deg); per-block exclusive scan
//   K3 scan2  : scan block sums
//   K4 scan3  : add block offsets
//   K5 gemm1  : h1 = x @ W1 (LDS-staged)
//   K6 scatter: pairs[off[c]+rank[e]] = (r, dinv[r]*w*dinv[c])  (no atomics)
//   K7 gather1: per-dst wave: acc = dinv^2*h1[dst] + sum norm*h1[src]
//               fused relu+b1, dot W2 -> h2[dst]; out[dst] = b2 + h2*dinv^2
//   K8 gather2: per-dst thread: out[dst] += sum norm*h2[src]

#define N_NODES 100000
#define N_EDGES 1600000
#define SCAN_BLOCKS 391   // ceil(100000/256)
#define CNT_SHIFT 42
#define SUM_MASK ((1ull << CNT_SHIFT) - 1)

__global__ void init_zero(int* __restrict__ p, int n) {
    int i = blockIdx.x * blockDim.x + threadIdx.x;
    if (i < n) p[i] = 0;
}

// One packed 64-bit atomic per edge; returns old -> rank within destination.
__global__ void hist_rank(const int* __restrict__ idx, const float* __restrict__ w,
                          unsigned long long* __restrict__ packed,
                          int* __restrict__ rank, int E) {
    int e = blockIdx.x * blockDim.x + threadIdx.x;
    if (e >= E) return;
    int c = idx[E + e];
    // w in [0,1): w * 2^32 is exact in f32 (power-of-2 scale); trunc error <= 2^-32.
    unsigned long long add =
        (1ull << CNT_SHIFT) | (unsigned long long)(w[e] * 4294967296.0f);
    unsigned long long old = atomicAdd(&packed[c], add);
    rank[e] = (int)(old >> CNT_SHIFT);
}

// Unpack packed -> cnt, dinv; per-block exclusive scan of cnt -> off, bsum.
__global__ void scan1(const unsigned long long* __restrict__ packed,
                      int* __restrict__ cnt, float* __restrict__ dinv,
                      int* __restrict__ off, int* __restrict__ bsum, int n) {
    __shared__ int s[256];
    int t = threadIdx.x;
    int i = blockIdx.x * 256 + t;
    unsigned long long p = (i < n) ? packed[i] : 0ull;
    int v = (int)(p >> CNT_SHIFT);
    if (i < n) {
        float deg = 1.0f + (float)(p & SUM_MASK) * 2.3283064365386963e-10f; // *2^-32
        dinv[i] = rsqrtf(deg);
        cnt[i] = v;
    }
    s[t] = v;
    __syncthreads();
#pragma unroll
    for (int d = 1; d < 256; d <<= 1) {
        int u = (t >= d) ? s[t - d] : 0;
        __syncthreads();
        s[t] += u;
        __syncthreads();
    }
    if (i < n) off[i] = s[t] - v;
    if (t == 255) bsum[blockIdx.x] = s[255];
}

// Exclusive scan of block totals (single block, 512 threads >= SCAN_BLOCKS).
__global__ void scan2(int* __restrict__ bsum, int nb) {
    __shared__ int s[512];
    int t = threadIdx.x;
    int v = (t < nb) ? bsum[t] : 0;
    s[t] = v;
    __syncthreads();
#pragma unroll
    for (int d = 1; d < 512; d <<= 1) {
        int u = (t >= d) ? s[t - d] : 0;
        __syncthreads();
        s[t] += u;
        __syncthreads();
    }
    if (t < nb) bsum[t] = s[t] - v;
}

__global__ void scan3(int* __restrict__ off, const int* __restrict__ bsum, int n) {
    int i = blockIdx.x * 256 + threadIdx.x;
    if (i < n) off[i] += bsum[blockIdx.x];
}

// 16 rows/block; W1 (16KB) + 16 x-rows (4KB) in LDS. Writes h1 only.
__global__ void gemm1(const float* __restrict__ x, const float* __restrict__ W1,
                      float* __restrict__ h1) {
    __shared__ float w1s[64 * 64];
    __shared__ float xs[16 * 64];
    int t = threadIdx.x;
    int row0 = blockIdx.x * 16;

    const float4* W4 = (const float4*)W1;
    float4* w1s4 = (float4*)w1s;
#pragma unroll
    for (int i = 0; i < 4; i++) w1s4[t + 256 * i] = W4[t + 256 * i];
    ((float4*)xs)[t] = ((const float4*)(x + (size_t)row0 * 64))[t];
    __syncthreads();

    int col = t & 63;
    int r0 = t >> 6;
    float acc0 = 0.f, acc1 = 0.f, acc2 = 0.f, acc3 = 0.f;
#pragma unroll
    for (int k = 0; k < 64; k++) {
        float wv = w1s[k * 64 + col];
        acc0 += xs[(r0     ) * 64 + k] * wv;
        acc1 += xs[(r0 +  4) * 64 + k] * wv;
        acc2 += xs[(r0 +  8) * 64 + k] * wv;
        acc3 += xs[(r0 + 12) * 64 + k] * wv;
    }
    float accs[4] = {acc0, acc1, acc2, acc3};
#pragma unroll
    for (int j = 0; j < 4; j++)
        h1[(size_t)(row0 + r0 + 4 * j) * 64 + col] = accs[j];
}

// Atomic-free placement using precomputed rank.
__global__ void scatter(const int* __restrict__ idx, const float* __restrict__ w,
                        const float* __restrict__ dinv, const int* __restrict__ off,
                        const int* __restrict__ rank, float2* __restrict__ pairs,
                        int E) {
    int e = blockIdx.x * blockDim.x + threadIdx.x;
    if (e >= E) return;
    int r = idx[e];
    int c = idx[E + e];
    float norm = dinv[r] * w[e] * dinv[c];
    pairs[off[c] + rank[e]] = make_float2(__int_as_float(r), norm);
}

// One wave per dst: 64-channel gather-aggregate, fused relu+b1+W2 projection.
__global__ void gather1(const float* __restrict__ h1, const float2* __restrict__ pairs,
                        const int* __restrict__ off, const int* __restrict__ cnt,
                        const float* __restrict__ dinv, const float* __restrict__ b1,
                        const float* __restrict__ W2, const float* __restrict__ b2,
                        float* __restrict__ h2, float* __restrict__ out, int n) {
    int t = threadIdx.x;
    int lane = t & 63;
    int dst = blockIdx.x * 4 + (t >> 6);
    if (dst >= n) return;
    int beg = off[dst];
    int end = beg + cnt[dst];
    float di = dinv[dst];
    float acc = h1[(size_t)dst * 64 + lane] * di * di;   // self-loop term
    float a0 = 0.f, a1 = 0.f, a2 = 0.f, a3 = 0.f;
    int j = beg;
    for (; j + 4 <= end; j += 4) {
        float2 p0 = pairs[j], p1 = pairs[j + 1], p2 = pairs[j + 2], p3 = pairs[j + 3];
        float v0 = h1[(size_t)__float_as_int(p0.x) * 64 + lane];
        float v1 = h1[(size_t)__float_as_int(p1.x) * 64 + lane];
        float v2 = h1[(size_t)__float_as_int(p2.x) * 64 + lane];
        float v3 = h1[(size_t)__float_as_int(p3.x) * 64 + lane];
        a0 += p0.y * v0; a1 += p1.y * v1; a2 += p2.y * v2; a3 += p3.y * v3;
    }
    for (; j < end; j++) {
        float2 p = pairs[j];
        a0 += p.y * h1[(size_t)__float_as_int(p.x) * 64 + lane];
    }
    acc += (a0 + a1) + (a2 + a3);
    float v = fmaxf(acc + b1[lane], 0.0f);
    float p = v * W2[lane];
#pragma unroll
    for (int offl = 32; offl > 0; offl >>= 1) p += __shfl_xor(p, offl, 64);
    if (lane == 0) {
        h2[dst] = p;
        out[dst] = b2[0] + p * di * di;   // bias + layer-2 self-loop
    }
}

// One thread per dst: out[dst] += sum norm * h2[src].
__global__ void gather2(const float2* __restrict__ pairs, const int* __restrict__ off,
                        const int* __restrict__ cnt, const float* __restrict__ h2,
                        float* __restrict__ out, int n) {
    int i = blockIdx.x * blockDim.x + threadIdx.x;
    if (i >= n) return;
    int beg = off[i];
    int end = beg + cnt[i];
    float s = 0.f;
#pragma unroll 4
    for (int j = beg; j < end; j++) {
        float2 p = pairs[j];
        s += p.y * h2[__float_as_int(p.x)];
    }
    out[i] += s;
}

extern "C" void kernel_launch(void* const* d_in, const int* in_sizes, int n_in,
                              void* d_out, int out_size, void* d_ws, size_t ws_size,
                              hipStream_t stream) {
    const float* x   = (const float*)d_in[0];
    const int*   idx = (const int*)d_in[1];      // int32 per harness contract
    const float* ew  = (const float*)d_in[2];
    const float* W1  = (const float*)d_in[3];
    const float* b1  = (const float*)d_in[4];
    const float* W2  = (const float*)d_in[5];
    const float* b2  = (const float*)d_in[6];
    float* out = (float*)d_out;

    const int N = N_NODES;
    const int E = N_EDGES;

    // ws layout (float units):
    // packed[2N] | rank[E] | off[N] | cnt[N] | dinv[N] | bsum[512] | pairs[2E] | h1[64N] | h2[N]
    float* ws = (float*)d_ws;
    unsigned long long* packed = (unsigned long long*)ws;        // 8B-aligned at 0
    int*    rank = (int*)(ws + 2 * (size_t)N);
    int*    off  = (int*)(ws + 2 * (size_t)N + E);
    int*    cnt  = (int*)(ws + 3 * (size_t)N + E);
    float*  dinv = ws + 4 * (size_t)N + E;
    int*    bsum = (int*)(ws + 5 * (size_t)N + E);               // 512 ints
    float2* pairs = (float2*)(ws + 5 * (size_t)N + E + 512);     // 8B-aligned
    float*  h1 = ws + 5 * (size_t)N + E + 512 + 2 * (size_t)E;   // 16B-aligned
    float*  h2 = h1 + (size_t)N * 64;
    // total = 11,800,512 floats = 47.2 MB

    init_zero<<<(2 * N + 255) / 256, 256, 0, stream>>>((int*)packed, 2 * N);
    hist_rank<<<(E + 255) / 256, 256, 0, stream>>>(idx, ew, packed, rank, E);
    scan1<<<SCAN_BLOCKS, 256, 0, stream>>>(packed, cnt, dinv, off, bsum, N);
    scan2<<<1, 512, 0, stream>>>(bsum, SCAN_BLOCKS);
    scan3<<<SCAN_BLOCKS, 256, 0, stream>>>(off, bsum, N);
    gemm1<<<N / 16, 256, 0, stream>>>(x, W1, h1);
    scatter<<<(E + 255) / 256, 256, 0, stream>>>(idx, ew, dinv, off, rank, pairs, E);
    gather1<<<(N + 3) / 4, 256, 0, stream>>>(h1, pairs, off, cnt, dinv, b1, W2, b2, h2, out, N);
    gather2<<<(N + 255) / 256, 256, 0, stream>>>(pairs, off, cnt, h2, out, N);
}